// Round 7
// baseline (658.708 us; speedup 1.0000x reference)
//
#include <hip/hip_runtime.h>
#include <math.h>

#define N_NODES 100000
#define N_EDGES 1600000
#define F_INF   128
#define HIDF    128

typedef __attribute__((ext_vector_type(8)))  short short8;
typedef __attribute__((ext_vector_type(16))) float floatx16;

__device__ __forceinline__ unsigned short f2bf(float f) {
    unsigned u = __float_as_uint(f);
    return (unsigned short)((u + 0x7FFFu + ((u >> 16) & 1u)) >> 16);
}

// ---------------------------------------------------------------- edge MLP
// 32 lanes per edge, 2 edges per wave, 4 hidden units per lane.
// Resident weights = 40 floats/lane (vs 80 in the 16-lane version whose 208
// VGPRs capped occupancy at 2 waves/SIMD -> 101 us). ~60 VGPRs here -> 8
// waves/SIMD, latency hidden.
__global__ __launch_bounds__(256) void k_edge_mlp(
        const float* __restrict__ ea,
        const float* __restrict__ w1, const float* __restrict__ b1,
        const float* __restrict__ w2, const float* __restrict__ b2,
        float* __restrict__ ew) {
    const int lane = threadIdx.x & 63;
    const int cl   = lane & 31;     // lane within edge-group (owns hidden cl*4..cl*4+3)
    const int half = lane >> 5;     // which of 2 edges this wave handles
    const int wid  = blockIdx.x * (blockDim.x >> 6) + (threadIdx.x >> 6);
    const int nw   = gridDim.x * (blockDim.x >> 6);

    // hidden units h = cl*4 + i ; w1 row-major [8][128] -> float4 loads
    float4 w1r[8];
#pragma unroll
    for (int k = 0; k < 8; ++k) w1r[k] = *(const float4*)(w1 + k * 128 + cl * 4);
    const float4 b1r = *(const float4*)(b1 + cl * 4);
    const float4 w2r = *(const float4*)(w2 + cl * 4);
    const float bias2 = b2[0];

    // N_EDGES % 2 == 0 and stride is a multiple of 2, so e = e0+half is in range.
    for (int e0 = wid * 2; e0 < N_EDGES; e0 += nw * 2) {
        const int e = e0 + half;
        const float4 a0 = *(const float4*)(ea + (size_t)e * 8);
        const float4 a1 = *(const float4*)(ea + (size_t)e * 8 + 4);
        const float a[8] = {a0.x, a0.y, a0.z, a0.w, a1.x, a1.y, a1.z, a1.w};
        float hx = b1r.x, hy = b1r.y, hz = b1r.z, hw = b1r.w;
#pragma unroll
        for (int k = 0; k < 8; ++k) {
            hx = fmaf(a[k], w1r[k].x, hx);
            hy = fmaf(a[k], w1r[k].y, hy);
            hz = fmaf(a[k], w1r[k].z, hz);
            hw = fmaf(a[k], w1r[k].w, hw);
        }
        float p = fmaxf(hx, 0.f) * w2r.x + fmaxf(hy, 0.f) * w2r.y
                + fmaxf(hz, 0.f) * w2r.z + fmaxf(hw, 0.f) * w2r.w;
        // reduce across the 32 lanes of this edge-group
        p += __shfl_xor(p, 1, 64);
        p += __shfl_xor(p, 2, 64);
        p += __shfl_xor(p, 4, 64);
        p += __shfl_xor(p, 8, 64);
        p += __shfl_xor(p, 16, 64);
        if (cl == 0) {
            const float z = p + bias2;
            ew[e] = 1.f / (1.f + __expf(-z));   // lanes 0,32 -> adjacent 4B words
        }
    }
}

// ---------------------------------------------------------------- CSR build
// k_deg: degree histogram + per-edge rank (order within its dst's slot range).
__global__ void k_deg(const int* __restrict__ dst, int* __restrict__ deg,
                      unsigned char* __restrict__ rank) {
    int e = blockIdx.x * 256 + threadIdx.x;
    if (e < N_EDGES) rank[e] = (unsigned char)atomicAdd(&deg[dst[e]], 1);
}

__global__ void k_scan1(const int* __restrict__ deg, int* __restrict__ incl,
                        int* __restrict__ bsum) {
    __shared__ int sm[1024];
    const int tid = threadIdx.x;
    const int gi  = blockIdx.x * 1024 + tid;
    int v = (gi < N_NODES) ? deg[gi] : 0;
    sm[tid] = v;
    __syncthreads();
    for (int off = 1; off < 1024; off <<= 1) {
        int t = (tid >= off) ? sm[tid - off] : 0;
        __syncthreads();
        sm[tid] += t;
        __syncthreads();
    }
    if (gi < N_NODES) incl[gi] = sm[tid];
    if (tid == 1023) bsum[blockIdx.x] = sm[1023];
}

__global__ void k_scan2(const int* __restrict__ bsum, int* __restrict__ boff, int nb) {
    __shared__ int sm[128];
    const int tid = threadIdx.x;
    int v = (tid < nb) ? bsum[tid] : 0;
    sm[tid] = v;
    __syncthreads();
    for (int off = 1; off < 128; off <<= 1) {
        int t = (tid >= off) ? sm[tid - off] : 0;
        __syncthreads();
        sm[tid] += t;
        __syncthreads();
    }
    boff[tid] = sm[tid] - v;
}

__global__ void k_scan3(const int* __restrict__ incl, const int* __restrict__ boff,
                        int* __restrict__ rowptr) {
    int i = blockIdx.x * 256 + threadIdx.x;
    if (i < N_NODES) rowptr[i + 1] = boff[i >> 10] + incl[i];
    if (i == 0) rowptr[0] = 0;
}

// k_fill: single 4B packed scatter per edge: (src:17 bits << 15) | bf16(ew)>>1
// (ew = sigmoid > 0 so its bf16 sign bit is 0 -> 15 bits suffice). No atomics.
__global__ void k_fill(const int* __restrict__ src, const int* __restrict__ dst,
                       const float* __restrict__ ew, const int* __restrict__ rowptr,
                       const unsigned char* __restrict__ rank,
                       unsigned* __restrict__ cw) {
    int e = blockIdx.x * 256 + threadIdx.x;
    if (e < N_EDGES) {
        int d   = dst[e];
        int pos = rowptr[d] + (int)rank[e];
        unsigned wb = (unsigned)f2bf(ew[e]) & 0x7FFFu;
        cw[pos] = ((unsigned)src[e] << 15) | wb;
    }
}

// ---------------------------------------------------------------- fp32 -> bf16 cast
__global__ void k_cast(const float* __restrict__ x, unsigned short* __restrict__ xb) {
    const int i = (blockIdx.x * 256 + threadIdx.x) * 4;  // N*128 % 4 == 0
    const float4 v = *(const float4*)(x + i);
    ushort4 o;
    o.x = f2bf(v.x); o.y = f2bf(v.y); o.z = f2bf(v.z); o.w = f2bf(v.w);
    *(ushort4*)(xb + i) = o;
}

// ---------------------------------------------------------------- aggregation (bf16 gather)
// wave per node; 32 lanes per edge (lane reads 8 B = 4 bf16), 2 edges per
// wave-instruction, 4-deep unroll => 8 edges in flight. Cross-half reduce at end.
__global__ __launch_bounds__(256) void k_agg16(
        const unsigned short* __restrict__ xb, const int* __restrict__ rowptr,
        const unsigned* __restrict__ cw, float* __restrict__ aggout) {
    const int lane = threadIdx.x & 63;
    const int half = lane >> 5;          // which edge of the pair
    const int cl   = lane & 31;          // cols cl*4 .. cl*4+3
    const int node = blockIdx.x * (blockDim.x >> 6) + (threadIdx.x >> 6);
    if (node >= N_NODES) return;
    const int s = rowptr[node], e = rowptr[node + 1];
    float a0 = 0.f, a1 = 0.f, a2 = 0.f, a3 = 0.f;

    for (int j0 = s; j0 < e; j0 += 8) {
        int ss[4]; float ww[4];
#pragma unroll
        for (int u = 0; u < 4; ++u) {
            const int j  = j0 + 2 * u + half;
            const int jc = min(j, e - 1);
            const unsigned p = cw[jc];
            ss[u] = (int)(p >> 15);
            ww[u] = (j < e) ? __uint_as_float((p & 0x7FFFu) << 16) : 0.f;
        }
        uint2 g[4];
#pragma unroll
        for (int u = 0; u < 4; ++u)
            g[u] = *(const uint2*)(xb + (size_t)ss[u] * 128 + cl * 4);
#pragma unroll
        for (int u = 0; u < 4; ++u) {
            const float f0 = __uint_as_float(g[u].x << 16);
            const float f1 = __uint_as_float(g[u].x & 0xFFFF0000u);
            const float f2 = __uint_as_float(g[u].y << 16);
            const float f3 = __uint_as_float(g[u].y & 0xFFFF0000u);
            a0 = fmaf(ww[u], f0, a0);
            a1 = fmaf(ww[u], f1, a1);
            a2 = fmaf(ww[u], f2, a2);
            a3 = fmaf(ww[u], f3, a3);
        }
    }
    a0 += __shfl_xor(a0, 32, 64);
    a1 += __shfl_xor(a1, 32, 64);
    a2 += __shfl_xor(a2, 32, 64);
    a3 += __shfl_xor(a3, 32, 64);
    if (half == 0) {
        const float inv = 1.f / fmaxf((float)(e - s), 1.f);
        float4 r;
        r.x = a0 * inv; r.y = a1 * inv; r.z = a2 * inv; r.w = a3 * inv;
        *(float4*)(aggout + (size_t)node * 128 + cl * 4) = r;
    }
}

// ---------------------------------------------------------------- W packing
// Pack [Wl;Wr] into MFMA B-fragment order (v_mfma_f32_32x32x16_bf16), hi/lo split.
__global__ void k_wpack(const float* __restrict__ Wl, const float* __restrict__ Wr,
                        short* __restrict__ Whi, short* __restrict__ Wlo) {
    int idx = blockIdx.x * 256 + threadIdx.x;   // 32768 total
    int j  = idx & 7;
    int L  = (idx >> 3) & 63;
    int cb = (idx >> 9) & 3;
    int kb = (idx >> 11);
    int k  = kb * 16 + (L >> 5) * 8 + j;
    int n  = cb * 32 + (L & 31);
    float a = (k < 128) ? Wl[k * 128 + n] : Wr[(k - 128) * 128 + n];
    unsigned short hb = f2bf(a);
    float hf = __uint_as_float((unsigned)hb << 16);
    Whi[idx] = (short)hb;
    Wlo[idx] = (short)f2bf(a - hf);
}

// ---------------------------------------------------------------- MFMA GEMM
// h = relu(bn(agg@Wl + b_l + x@Wr)), K=256, split-bf16 (3 MFMA per frag).
// Dual-output epilogue: fp32 `out` + optional bf16 `out16` for next layer's gather.
__global__ __launch_bounds__(256) void k_gemm_mfma(
    const float* __restrict__ Aagg, const float* __restrict__ Ax,
    const short* __restrict__ Whi, const short* __restrict__ Wlo,
    const float* __restrict__ bl,
    const float* __restrict__ bng, const float* __restrict__ bnb,
    const float* __restrict__ bnm, const float* __restrict__ bnv,
    float* __restrict__ out, unsigned short* __restrict__ out16) {
    const int tid  = threadIdx.x;
    const int lane = tid & 63;
    const int w    = tid >> 6;
    const int row0 = blockIdx.x * 128 + w * 32;
    const int rrow = lane & 31;
    const int kq   = lane >> 5;
    const int arow = min(row0 + rrow, N_NODES - 1);

    floatx16 acc[4];
#pragma unroll
    for (int cb = 0; cb < 4; ++cb)
#pragma unroll
        for (int r = 0; r < 16; ++r) acc[cb][r] = 0.f;

    const float* Abase0 = Aagg + (size_t)arow * 128 + kq * 8;
    const float* Abase1 = Ax   + (size_t)arow * 128 + kq * 8;

#pragma unroll 2
    for (int kb = 0; kb < 16; ++kb) {
        const float* ap = ((kb < 8) ? Abase0 : Abase1) + (kb & 7) * 16;
        const float4 a0 = *(const float4*)(ap);
        const float4 a1 = *(const float4*)(ap + 4);
        const float av[8] = {a0.x, a0.y, a0.z, a0.w, a1.x, a1.y, a1.z, a1.w};
        short8 Ah, Al;
#pragma unroll
        for (int j = 0; j < 8; ++j) {
            unsigned short hb = f2bf(av[j]);
            float hf = __uint_as_float((unsigned)hb << 16);
            Ah[j] = (short)hb;
            Al[j] = (short)f2bf(av[j] - hf);
        }
#pragma unroll
        for (int cb = 0; cb < 4; ++cb) {
            const size_t wo = ((size_t)(kb * 4 + cb) * 64 + lane) * 8;
            const short8 wh = *(const short8*)(Whi + wo);
            const short8 wl = *(const short8*)(Wlo + wo);
            acc[cb] = __builtin_amdgcn_mfma_f32_32x32x16_bf16(Ah, wh, acc[cb], 0, 0, 0);
            acc[cb] = __builtin_amdgcn_mfma_f32_32x32x16_bf16(Al, wh, acc[cb], 0, 0, 0);
            acc[cb] = __builtin_amdgcn_mfma_f32_32x32x16_bf16(Ah, wl, acc[cb], 0, 0, 0);
        }
    }

#pragma unroll
    for (int cb = 0; cb < 4; ++cb) {
        const int c = cb * 32 + (lane & 31);
        const float s = bng[c] * rsqrtf(bnv[c] + 1e-5f);
        const float t = (bl[c] - bnm[c]) * s + bnb[c];
#pragma unroll
        for (int r = 0; r < 16; ++r) {
            const int row = row0 + (r & 3) + 8 * (r >> 2) + 4 * kq;
            if (row < N_NODES) {
                const float v = fmaxf(fmaf(acc[cb][r], s, t), 0.f);
                out[(size_t)row * 128 + c] = v;
                if (out16) out16[(size_t)row * 128 + c] = f2bf(v);
            }
        }
    }
}

// ---------------------------------------------------------------- layer 3
__global__ void k_lin3(const float* __restrict__ h, const float* __restrict__ w3l,
                       const float* __restrict__ w3r, float* __restrict__ t4) {
    const int lane = threadIdx.x & 63;
    const int node = blockIdx.x * (blockDim.x >> 6) + (threadIdx.x >> 6);
    if (node >= N_NODES) return;
    float h0 = h[(size_t)node * 128 + lane];
    float h1 = h[(size_t)node * 128 + 64 + lane];
    float2 wl0 = *(const float2*)(w3l + lane * 2);
    float2 wl1 = *(const float2*)(w3l + (64 + lane) * 2);
    float2 wr0 = *(const float2*)(w3r + lane * 2);
    float2 wr1 = *(const float2*)(w3r + (64 + lane) * 2);
    float p0 = h0 * wl0.x + h1 * wl1.x;
    float p1 = h0 * wl0.y + h1 * wl1.y;
    float p2 = h0 * wr0.x + h1 * wr1.x;
    float p3 = h0 * wr0.y + h1 * wr1.y;
#pragma unroll
    for (int m = 1; m < 64; m <<= 1) {
        p0 += __shfl_xor(p0, m, 64);
        p1 += __shfl_xor(p1, m, 64);
        p2 += __shfl_xor(p2, m, 64);
        p3 += __shfl_xor(p3, m, 64);
    }
    if (lane == 0) {
        float4 o; o.x = p0; o.y = p1; o.z = p2; o.w = p3;
        *(float4*)(t4 + (size_t)node * 4) = o;
    }
}

__global__ void k_out(const float* __restrict__ t4, const int* __restrict__ rowptr,
                      const unsigned* __restrict__ cw,
                      const float* __restrict__ b3, float* __restrict__ out) {
    const int lane = threadIdx.x & 63;
    const int node = blockIdx.x * (blockDim.x >> 6) + (threadIdx.x >> 6);
    if (node >= N_NODES) return;
    const int s = rowptr[node], e = rowptr[node + 1];
    float a0 = 0.f, a1 = 0.f;
    for (int j = s + lane; j < e; j += 64) {
        const unsigned p = cw[j];
        const int   sr = (int)(p >> 15);
        const float w  = __uint_as_float((p & 0x7FFFu) << 16);
        float2 t = *(const float2*)(t4 + (size_t)sr * 4);
        a0 += w * t.x; a1 += w * t.y;
    }
#pragma unroll
    for (int m = 1; m < 64; m <<= 1) {
        a0 += __shfl_xor(a0, m, 64);
        a1 += __shfl_xor(a1, m, 64);
    }
    if (lane == 0) {
        float inv = 1.f / fmaxf((float)(e - s), 1.f);
        float2 o;
        o.x = a0 * inv + b3[0] + t4[(size_t)node * 4 + 2];
        o.y = a1 * inv + b3[1] + t4[(size_t)node * 4 + 3];
        *(float2*)(out + (size_t)node * 2) = o;
    }
}

// ---------------------------------------------------------------- launch
extern "C" void kernel_launch(void* const* d_in, const int* in_sizes, int n_in,
                              void* d_out, int out_size, void* d_ws, size_t ws_size,
                              hipStream_t stream) {
    const float* x    = (const float*)d_in[0];
    const float* ea   = (const float*)d_in[1];
    const int*   ei   = (const int*)d_in[2];
    const float* ew1w = (const float*)d_in[3];
    const float* ew1b = (const float*)d_in[4];
    const float* ew2w = (const float*)d_in[5];
    const float* ew2b = (const float*)d_in[6];
    const float* w1l  = (const float*)d_in[7];
    const float* b1l  = (const float*)d_in[8];
    const float* w1r  = (const float*)d_in[9];
    const float* w2l  = (const float*)d_in[10];
    const float* b2l  = (const float*)d_in[11];
    const float* w2r  = (const float*)d_in[12];
    const float* w3l  = (const float*)d_in[13];
    const float* b3l  = (const float*)d_in[14];
    const float* w3r  = (const float*)d_in[15];
    const float* bn1g = (const float*)d_in[16];
    const float* bn1b = (const float*)d_in[17];
    const float* bn1m = (const float*)d_in[18];
    const float* bn1v = (const float*)d_in[19];
    const float* bn2g = (const float*)d_in[20];
    const float* bn2b = (const float*)d_in[21];
    const float* bn2m = (const float*)d_in[22];
    const float* bn2v = (const float*)d_in[23];

    const int* src = ei;
    const int* dst = ei + N_EDGES;
    float* out = (float*)d_out;

    size_t off = 0;
    auto carve = [&](size_t bytes) -> void* {
        void* p = (char*)d_ws + off;
        off += (bytes + 255) & ~(size_t)255;
        return p;
    };
    float* ew     = (float*)carve((size_t)N_EDGES * 4);
    unsigned* cw  = (unsigned*)carve((size_t)N_EDGES * 4);
    unsigned char* rank = (unsigned char*)carve((size_t)N_EDGES);
    int*   rowptr = (int*)carve((size_t)(N_NODES + 1) * 4);
    int*   deg    = (int*)carve((size_t)N_NODES * 4);
    int*   bsum   = (int*)carve(128 * 4);
    int*   boff   = (int*)carve(128 * 4);
    int*   incl   = (int*)carve((size_t)N_NODES * 4);
    float* agg    = (float*)carve((size_t)N_NODES * 128 * 4);
    float* hA     = (float*)carve((size_t)N_NODES * 128 * 4);
    float* hB     = (float*)carve((size_t)N_NODES * 128 * 4);
    float* t4     = (float*)carve((size_t)N_NODES * 4 * 4);
    short* W1hi   = (short*)carve(32768 * 2);
    short* W1lo   = (short*)carve(32768 * 2);
    short* W2hi   = (short*)carve(32768 * 2);
    short* W2lo   = (short*)carve(32768 * 2);
    unsigned short* xb   = (unsigned short*)carve((size_t)N_NODES * 128 * 2);
    unsigned short* hA16 = (unsigned short*)carve((size_t)N_NODES * 128 * 2);
    (void)ws_size; (void)n_in; (void)in_sizes; (void)out_size;

    hipMemsetAsync(deg, 0, (size_t)N_NODES * 4, stream);

    const int EB = (N_EDGES + 255) / 256;        // 6250
    const int NB_SCAN = (N_NODES + 1023) / 1024; // 98
    const int NWB = (N_NODES + 3) / 4;           // 25000
    const int GB = (N_NODES + 127) / 128;        // 782
    const int CB = (N_NODES * 128 / 4 + 255) / 256;  // 12500

    k_deg<<<EB, 256, 0, stream>>>(dst, deg, rank);
    k_cast<<<CB, 256, 0, stream>>>(x, xb);
    k_edge_mlp<<<2048, 256, 0, stream>>>(ea, ew1w, ew1b, ew2w, ew2b, ew);
    k_wpack<<<128, 256, 0, stream>>>(w1l, w1r, W1hi, W1lo);
    k_wpack<<<128, 256, 0, stream>>>(w2l, w2r, W2hi, W2lo);
    k_scan1<<<NB_SCAN, 1024, 0, stream>>>(deg, incl, bsum);
    k_scan2<<<1, 128, 0, stream>>>(bsum, boff, NB_SCAN);
    k_scan3<<<(N_NODES + 255) / 256, 256, 0, stream>>>(incl, boff, rowptr);
    k_fill<<<EB, 256, 0, stream>>>(src, dst, ew, rowptr, rank, cw);

    // layer 1
    k_agg16<<<NWB, 256, 0, stream>>>(xb, rowptr, cw, agg);
    k_gemm_mfma<<<GB, 256, 0, stream>>>(agg, x, W1hi, W1lo, b1l,
                                        bn1g, bn1b, bn1m, bn1v, hA, hA16);
    // layer 2
    k_agg16<<<NWB, 256, 0, stream>>>(hA16, rowptr, cw, agg);
    k_gemm_mfma<<<GB, 256, 0, stream>>>(agg, hA, W2hi, W2lo, b2l,
                                        bn2g, bn2b, bn2m, bn2v, hB, nullptr);
    // layer 3 (transform-then-aggregate: only 2 floats/edge)
    k_lin3<<<NWB, 256, 0, stream>>>(hB, w3l, w3r, t4);
    k_out<<<NWB, 256, 0, stream>>>(t4, rowptr, cw, b3l, out);
}

// Round 8
// 594.282 us; speedup vs baseline: 1.1084x; 1.1084x over previous
//
#include <hip/hip_runtime.h>
#include <math.h>

#define N_NODES 100000
#define N_EDGES 1600000
#define F_INF   128
#define HIDF    128

typedef __attribute__((ext_vector_type(8)))  short short8;
typedef __attribute__((ext_vector_type(16))) float floatx16;

__device__ __forceinline__ unsigned short f2bf(float f) {
    unsigned u = __float_as_uint(f);
    return (unsigned short)((u + 0x7FFFu + ((u >> 16) & 1u)) >> 16);
}

// ---------------------------------------------------------------- edge MLP
// MFMA formulation: one wave = 32 edges per iteration.
// Layer 1 ([E,8]@[8,128]) via 4x v_mfma_f32_32x32x16_bf16: A = 32 edges x K16
// (k=0..7 attrs, k=8 = constant-1 "bias activation" whose B-row is b1, k>8 zero;
// lanes>=32 carry the k=8..15 half). Layer 2 (128->1) in fp32 on the C-frags +
// 32-lane butterfly. Replaces the ~70 VALU-instr/edge scalar version (128 us,
// issue-bound) with ~11 VALU + 0.125 MFMA per edge.
__global__ __launch_bounds__(256) void k_edge_mlp(
        const float* __restrict__ ea,
        const float* __restrict__ w1, const float* __restrict__ b1,
        const float* __restrict__ w2, const float* __restrict__ b2,
        float* __restrict__ ew) {
    const int lane = threadIdx.x & 63;
    const int cl   = lane & 31;
    const int half = lane >> 5;
    const int wid  = blockIdx.x * (blockDim.x >> 6) + (threadIdx.x >> 6);
    const int nw   = gridDim.x * (blockDim.x >> 6);

    // B fragments: B[k][n], n = cb*32+cl, k = 8*half + j. k<8: w1; k==8: b1; else 0.
    short8 bw[4];
    float  w2c[4];
#pragma unroll
    for (int cb = 0; cb < 4; ++cb) {
        const int n = cb * 32 + cl;
        short8 b;
        if (half == 0) {
#pragma unroll
            for (int j = 0; j < 8; ++j) b[j] = (short)f2bf(w1[j * 128 + n]);
        } else {
            b[0] = (short)f2bf(b1[n]);
#pragma unroll
            for (int j = 1; j < 8; ++j) b[j] = 0;
        }
        bw[cb] = b;
        w2c[cb] = w2[n];
    }
    // A-frag for the pad half: k=8 -> 1.0 (bias activation), k=9..15 -> 0.
    short8 Abias;
    Abias[0] = (short)0x3F80;
#pragma unroll
    for (int j = 1; j < 8; ++j) Abias[j] = 0;

    floatx16 czero;
#pragma unroll
    for (int r = 0; r < 16; ++r) czero[r] = 0.f;

    const float bias2 = b2[0];

    // N_EDGES % 32 == 0; stride is a multiple of 32.
    for (int e0 = wid * 32; e0 < N_EDGES; e0 += nw * 32) {
        short8 Ah;
        if (half == 0) {
            const float4 a0 = *(const float4*)(ea + (size_t)(e0 + cl) * 8);
            const float4 a1 = *(const float4*)(ea + (size_t)(e0 + cl) * 8 + 4);
            Ah[0] = (short)f2bf(a0.x); Ah[1] = (short)f2bf(a0.y);
            Ah[2] = (short)f2bf(a0.z); Ah[3] = (short)f2bf(a0.w);
            Ah[4] = (short)f2bf(a1.x); Ah[5] = (short)f2bf(a1.y);
            Ah[6] = (short)f2bf(a1.z); Ah[7] = (short)f2bf(a1.w);
        } else {
            Ah = Abias;
        }

        float z[16];
#pragma unroll
        for (int r = 0; r < 16; ++r) z[r] = 0.f;

#pragma unroll
        for (int cb = 0; cb < 4; ++cb) {
            floatx16 acc = __builtin_amdgcn_mfma_f32_32x32x16_bf16(Ah, bw[cb], czero, 0, 0, 0);
#pragma unroll
            for (int r = 0; r < 16; ++r)
                z[r] = fmaf(fmaxf(acc[r], 0.f), w2c[cb], z[r]);
        }

        // reduce z over the 32 lanes of this half (cols); rows stay per (reg, half)
#pragma unroll
        for (int m = 1; m <= 16; m <<= 1) {
#pragma unroll
            for (int r = 0; r < 16; ++r) z[r] += __shfl_xor(z[r], m, 64);
        }

        // lane cl<16 owns reg r=cl -> edge row (cl&3)+8*(cl>>2)+4*half
        float zz = z[0];
#pragma unroll
        for (int r = 1; r < 16; ++r) zz = (cl == r) ? z[r] : zz;
        if (cl < 16) {
            const int row = (cl & 3) + 8 * (cl >> 2) + 4 * half;
            ew[e0 + row] = 1.f / (1.f + __expf(-(zz + bias2)));
        }
    }
}

// ---------------------------------------------------------------- CSR build
// k_deg: degree histogram + per-edge rank (order within its dst's slot range).
__global__ void k_deg(const int* __restrict__ dst, int* __restrict__ deg,
                      unsigned char* __restrict__ rank) {
    int e = blockIdx.x * 256 + threadIdx.x;
    if (e < N_EDGES) rank[e] = (unsigned char)atomicAdd(&deg[dst[e]], 1);
}

__global__ void k_scan1(const int* __restrict__ deg, int* __restrict__ incl,
                        int* __restrict__ bsum) {
    __shared__ int sm[1024];
    const int tid = threadIdx.x;
    const int gi  = blockIdx.x * 1024 + tid;
    int v = (gi < N_NODES) ? deg[gi] : 0;
    sm[tid] = v;
    __syncthreads();
    for (int off = 1; off < 1024; off <<= 1) {
        int t = (tid >= off) ? sm[tid - off] : 0;
        __syncthreads();
        sm[tid] += t;
        __syncthreads();
    }
    if (gi < N_NODES) incl[gi] = sm[tid];
    if (tid == 1023) bsum[blockIdx.x] = sm[1023];
}

__global__ void k_scan2(const int* __restrict__ bsum, int* __restrict__ boff, int nb) {
    __shared__ int sm[128];
    const int tid = threadIdx.x;
    int v = (tid < nb) ? bsum[tid] : 0;
    sm[tid] = v;
    __syncthreads();
    for (int off = 1; off < 128; off <<= 1) {
        int t = (tid >= off) ? sm[tid - off] : 0;
        __syncthreads();
        sm[tid] += t;
        __syncthreads();
    }
    boff[tid] = sm[tid] - v;
}

__global__ void k_scan3(const int* __restrict__ incl, const int* __restrict__ boff,
                        int* __restrict__ rowptr) {
    int i = blockIdx.x * 256 + threadIdx.x;
    if (i < N_NODES) rowptr[i + 1] = boff[i >> 10] + incl[i];
    if (i == 0) rowptr[0] = 0;
}

// k_fill: single 4B packed scatter per edge: (src:17 bits << 15) | bf16(ew)>>1
// (ew = sigmoid > 0 so its bf16 sign bit is 0 -> 15 bits suffice). No atomics.
__global__ void k_fill(const int* __restrict__ src, const int* __restrict__ dst,
                       const float* __restrict__ ew, const int* __restrict__ rowptr,
                       const unsigned char* __restrict__ rank,
                       unsigned* __restrict__ cw) {
    int e = blockIdx.x * 256 + threadIdx.x;
    if (e < N_EDGES) {
        int d   = dst[e];
        int pos = rowptr[d] + (int)rank[e];
        unsigned wb = (unsigned)f2bf(ew[e]) & 0x7FFFu;
        cw[pos] = ((unsigned)src[e] << 15) | wb;
    }
}

// ---------------------------------------------------------------- fp32 -> bf16 cast
__global__ void k_cast(const float* __restrict__ x, unsigned short* __restrict__ xb) {
    const int i = (blockIdx.x * 256 + threadIdx.x) * 4;  // N*128 % 4 == 0
    const float4 v = *(const float4*)(x + i);
    ushort4 o;
    o.x = f2bf(v.x); o.y = f2bf(v.y); o.z = f2bf(v.z); o.w = f2bf(v.w);
    *(ushort4*)(xb + i) = o;
}

// ---------------------------------------------------------------- aggregation (bf16 gather)
// wave per node; 32 lanes per edge (lane reads 8 B = 4 bf16), 2 edges per
// wave-instruction, 4-deep unroll => 8 edges in flight. Cross-half reduce at end.
__global__ __launch_bounds__(256) void k_agg16(
        const unsigned short* __restrict__ xb, const int* __restrict__ rowptr,
        const unsigned* __restrict__ cw, float* __restrict__ aggout) {
    const int lane = threadIdx.x & 63;
    const int half = lane >> 5;          // which edge of the pair
    const int cl   = lane & 31;          // cols cl*4 .. cl*4+3
    const int node = blockIdx.x * (blockDim.x >> 6) + (threadIdx.x >> 6);
    if (node >= N_NODES) return;
    const int s = rowptr[node], e = rowptr[node + 1];
    float a0 = 0.f, a1 = 0.f, a2 = 0.f, a3 = 0.f;

    for (int j0 = s; j0 < e; j0 += 8) {
        int ss[4]; float ww[4];
#pragma unroll
        for (int u = 0; u < 4; ++u) {
            const int j  = j0 + 2 * u + half;
            const int jc = min(j, e - 1);
            const unsigned p = cw[jc];
            ss[u] = (int)(p >> 15);
            ww[u] = (j < e) ? __uint_as_float((p & 0x7FFFu) << 16) : 0.f;
        }
        uint2 g[4];
#pragma unroll
        for (int u = 0; u < 4; ++u)
            g[u] = *(const uint2*)(xb + (size_t)ss[u] * 128 + cl * 4);
#pragma unroll
        for (int u = 0; u < 4; ++u) {
            const float f0 = __uint_as_float(g[u].x << 16);
            const float f1 = __uint_as_float(g[u].x & 0xFFFF0000u);
            const float f2 = __uint_as_float(g[u].y << 16);
            const float f3 = __uint_as_float(g[u].y & 0xFFFF0000u);
            a0 = fmaf(ww[u], f0, a0);
            a1 = fmaf(ww[u], f1, a1);
            a2 = fmaf(ww[u], f2, a2);
            a3 = fmaf(ww[u], f3, a3);
        }
    }
    a0 += __shfl_xor(a0, 32, 64);
    a1 += __shfl_xor(a1, 32, 64);
    a2 += __shfl_xor(a2, 32, 64);
    a3 += __shfl_xor(a3, 32, 64);
    if (half == 0) {
        const float inv = 1.f / fmaxf((float)(e - s), 1.f);
        float4 r;
        r.x = a0 * inv; r.y = a1 * inv; r.z = a2 * inv; r.w = a3 * inv;
        *(float4*)(aggout + (size_t)node * 128 + cl * 4) = r;
    }
}

// ---------------------------------------------------------------- W packing
// Pack [Wl;Wr] into MFMA B-fragment order (v_mfma_f32_32x32x16_bf16), hi/lo split.
__global__ void k_wpack(const float* __restrict__ Wl, const float* __restrict__ Wr,
                        short* __restrict__ Whi, short* __restrict__ Wlo) {
    int idx = blockIdx.x * 256 + threadIdx.x;   // 32768 total
    int j  = idx & 7;
    int L  = (idx >> 3) & 63;
    int cb = (idx >> 9) & 3;
    int kb = (idx >> 11);
    int k  = kb * 16 + (L >> 5) * 8 + j;
    int n  = cb * 32 + (L & 31);
    float a = (k < 128) ? Wl[k * 128 + n] : Wr[(k - 128) * 128 + n];
    unsigned short hb = f2bf(a);
    float hf = __uint_as_float((unsigned)hb << 16);
    Whi[idx] = (short)hb;
    Wlo[idx] = (short)f2bf(a - hf);
}

// ---------------------------------------------------------------- MFMA GEMM
// h = relu(bn(agg@Wl + b_l + x@Wr)), K=256, split-bf16 (3 MFMA per frag).
// Dual-output epilogue: fp32 `out` + optional bf16 `out16` for next layer's gather.
__global__ __launch_bounds__(256) void k_gemm_mfma(
    const float* __restrict__ Aagg, const float* __restrict__ Ax,
    const short* __restrict__ Whi, const short* __restrict__ Wlo,
    const float* __restrict__ bl,
    const float* __restrict__ bng, const float* __restrict__ bnb,
    const float* __restrict__ bnm, const float* __restrict__ bnv,
    float* __restrict__ out, unsigned short* __restrict__ out16) {
    const int tid  = threadIdx.x;
    const int lane = tid & 63;
    const int w    = tid >> 6;
    const int row0 = blockIdx.x * 128 + w * 32;
    const int rrow = lane & 31;
    const int kq   = lane >> 5;
    const int arow = min(row0 + rrow, N_NODES - 1);

    floatx16 acc[4];
#pragma unroll
    for (int cb = 0; cb < 4; ++cb)
#pragma unroll
        for (int r = 0; r < 16; ++r) acc[cb][r] = 0.f;

    const float* Abase0 = Aagg + (size_t)arow * 128 + kq * 8;
    const float* Abase1 = Ax   + (size_t)arow * 128 + kq * 8;

#pragma unroll 2
    for (int kb = 0; kb < 16; ++kb) {
        const float* ap = ((kb < 8) ? Abase0 : Abase1) + (kb & 7) * 16;
        const float4 a0 = *(const float4*)(ap);
        const float4 a1 = *(const float4*)(ap + 4);
        const float av[8] = {a0.x, a0.y, a0.z, a0.w, a1.x, a1.y, a1.z, a1.w};
        short8 Ah, Al;
#pragma unroll
        for (int j = 0; j < 8; ++j) {
            unsigned short hb = f2bf(av[j]);
            float hf = __uint_as_float((unsigned)hb << 16);
            Ah[j] = (short)hb;
            Al[j] = (short)f2bf(av[j] - hf);
        }
#pragma unroll
        for (int cb = 0; cb < 4; ++cb) {
            const size_t wo = ((size_t)(kb * 4 + cb) * 64 + lane) * 8;
            const short8 wh = *(const short8*)(Whi + wo);
            const short8 wl = *(const short8*)(Wlo + wo);
            acc[cb] = __builtin_amdgcn_mfma_f32_32x32x16_bf16(Ah, wh, acc[cb], 0, 0, 0);
            acc[cb] = __builtin_amdgcn_mfma_f32_32x32x16_bf16(Al, wh, acc[cb], 0, 0, 0);
            acc[cb] = __builtin_amdgcn_mfma_f32_32x32x16_bf16(Ah, wl, acc[cb], 0, 0, 0);
        }
    }

#pragma unroll
    for (int cb = 0; cb < 4; ++cb) {
        const int c = cb * 32 + (lane & 31);
        const float s = bng[c] * rsqrtf(bnv[c] + 1e-5f);
        const float t = (bl[c] - bnm[c]) * s + bnb[c];
#pragma unroll
        for (int r = 0; r < 16; ++r) {
            const int row = row0 + (r & 3) + 8 * (r >> 2) + 4 * kq;
            if (row < N_NODES) {
                const float v = fmaxf(fmaf(acc[cb][r], s, t), 0.f);
                out[(size_t)row * 128 + c] = v;
                if (out16) out16[(size_t)row * 128 + c] = f2bf(v);
            }
        }
    }
}

// ---------------------------------------------------------------- layer 3
__global__ void k_lin3(const float* __restrict__ h, const float* __restrict__ w3l,
                       const float* __restrict__ w3r, float* __restrict__ t4) {
    const int lane = threadIdx.x & 63;
    const int node = blockIdx.x * (blockDim.x >> 6) + (threadIdx.x >> 6);
    if (node >= N_NODES) return;
    float h0 = h[(size_t)node * 128 + lane];
    float h1 = h[(size_t)node * 128 + 64 + lane];
    float2 wl0 = *(const float2*)(w3l + lane * 2);
    float2 wl1 = *(const float2*)(w3l + (64 + lane) * 2);
    float2 wr0 = *(const float2*)(w3r + lane * 2);
    float2 wr1 = *(const float2*)(w3r + (64 + lane) * 2);
    float p0 = h0 * wl0.x + h1 * wl1.x;
    float p1 = h0 * wl0.y + h1 * wl1.y;
    float p2 = h0 * wr0.x + h1 * wr1.x;
    float p3 = h0 * wr0.y + h1 * wr1.y;
#pragma unroll
    for (int m = 1; m < 64; m <<= 1) {
        p0 += __shfl_xor(p0, m, 64);
        p1 += __shfl_xor(p1, m, 64);
        p2 += __shfl_xor(p2, m, 64);
        p3 += __shfl_xor(p3, m, 64);
    }
    if (lane == 0) {
        float4 o; o.x = p0; o.y = p1; o.z = p2; o.w = p3;
        *(float4*)(t4 + (size_t)node * 4) = o;
    }
}

__global__ void k_out(const float* __restrict__ t4, const int* __restrict__ rowptr,
                      const unsigned* __restrict__ cw,
                      const float* __restrict__ b3, float* __restrict__ out) {
    const int lane = threadIdx.x & 63;
    const int node = blockIdx.x * (blockDim.x >> 6) + (threadIdx.x >> 6);
    if (node >= N_NODES) return;
    const int s = rowptr[node], e = rowptr[node + 1];
    float a0 = 0.f, a1 = 0.f;
    for (int j = s + lane; j < e; j += 64) {
        const unsigned p = cw[j];
        const int   sr = (int)(p >> 15);
        const float w  = __uint_as_float((p & 0x7FFFu) << 16);
        float2 t = *(const float2*)(t4 + (size_t)sr * 4);
        a0 += w * t.x; a1 += w * t.y;
    }
#pragma unroll
    for (int m = 1; m < 64; m <<= 1) {
        a0 += __shfl_xor(a0, m, 64);
        a1 += __shfl_xor(a1, m, 64);
    }
    if (lane == 0) {
        float inv = 1.f / fmaxf((float)(e - s), 1.f);
        float2 o;
        o.x = a0 * inv + b3[0] + t4[(size_t)node * 4 + 2];
        o.y = a1 * inv + b3[1] + t4[(size_t)node * 4 + 3];
        *(float2*)(out + (size_t)node * 2) = o;
    }
}

// ---------------------------------------------------------------- launch
extern "C" void kernel_launch(void* const* d_in, const int* in_sizes, int n_in,
                              void* d_out, int out_size, void* d_ws, size_t ws_size,
                              hipStream_t stream) {
    const float* x    = (const float*)d_in[0];
    const float* ea   = (const float*)d_in[1];
    const int*   ei   = (const int*)d_in[2];
    const float* ew1w = (const float*)d_in[3];
    const float* ew1b = (const float*)d_in[4];
    const float* ew2w = (const float*)d_in[5];
    const float* ew2b = (const float*)d_in[6];
    const float* w1l  = (const float*)d_in[7];
    const float* b1l  = (const float*)d_in[8];
    const float* w1r  = (const float*)d_in[9];
    const float* w2l  = (const float*)d_in[10];
    const float* b2l  = (const float*)d_in[11];
    const float* w2r  = (const float*)d_in[12];
    const float* w3l  = (const float*)d_in[13];
    const float* b3l  = (const float*)d_in[14];
    const float* w3r  = (const float*)d_in[15];
    const float* bn1g = (const float*)d_in[16];
    const float* bn1b = (const float*)d_in[17];
    const float* bn1m = (const float*)d_in[18];
    const float* bn1v = (const float*)d_in[19];
    const float* bn2g = (const float*)d_in[20];
    const float* bn2b = (const float*)d_in[21];
    const float* bn2m = (const float*)d_in[22];
    const float* bn2v = (const float*)d_in[23];

    const int* src = ei;
    const int* dst = ei + N_EDGES;
    float* out = (float*)d_out;

    size_t off = 0;
    auto carve = [&](size_t bytes) -> void* {
        void* p = (char*)d_ws + off;
        off += (bytes + 255) & ~(size_t)255;
        return p;
    };
    float* ew     = (float*)carve((size_t)N_EDGES * 4);
    unsigned* cw  = (unsigned*)carve((size_t)N_EDGES * 4);
    unsigned char* rank = (unsigned char*)carve((size_t)N_EDGES);
    int*   rowptr = (int*)carve((size_t)(N_NODES + 1) * 4);
    int*   deg    = (int*)carve((size_t)N_NODES * 4);
    int*   bsum   = (int*)carve(128 * 4);
    int*   boff   = (int*)carve(128 * 4);
    int*   incl   = (int*)carve((size_t)N_NODES * 4);
    float* agg    = (float*)carve((size_t)N_NODES * 128 * 4);
    float* hA     = (float*)carve((size_t)N_NODES * 128 * 4);
    float* hB     = (float*)carve((size_t)N_NODES * 128 * 4);
    float* t4     = (float*)carve((size_t)N_NODES * 4 * 4);
    short* W1hi   = (short*)carve(32768 * 2);
    short* W1lo   = (short*)carve(32768 * 2);
    short* W2hi   = (short*)carve(32768 * 2);
    short* W2lo   = (short*)carve(32768 * 2);
    unsigned short* xb   = (unsigned short*)carve((size_t)N_NODES * 128 * 2);
    unsigned short* hA16 = (unsigned short*)carve((size_t)N_NODES * 128 * 2);
    (void)ws_size; (void)n_in; (void)in_sizes; (void)out_size;

    hipMemsetAsync(deg, 0, (size_t)N_NODES * 4, stream);

    const int EB = (N_EDGES + 255) / 256;        // 6250
    const int NB_SCAN = (N_NODES + 1023) / 1024; // 98
    const int NWB = (N_NODES + 3) / 4;           // 25000
    const int GB = (N_NODES + 127) / 128;        // 782
    const int CB = (N_NODES * 128 / 4 + 255) / 256;  // 12500

    k_deg<<<EB, 256, 0, stream>>>(dst, deg, rank);
    k_cast<<<CB, 256, 0, stream>>>(x, xb);
    k_edge_mlp<<<2048, 256, 0, stream>>>(ea, ew1w, ew1b, ew2w, ew2b, ew);
    k_wpack<<<128, 256, 0, stream>>>(w1l, w1r, W1hi, W1lo);
    k_wpack<<<128, 256, 0, stream>>>(w2l, w2r, W2hi, W2lo);
    k_scan1<<<NB_SCAN, 1024, 0, stream>>>(deg, incl, bsum);
    k_scan2<<<1, 128, 0, stream>>>(bsum, boff, NB_SCAN);
    k_scan3<<<(N_NODES + 255) / 256, 256, 0, stream>>>(incl, boff, rowptr);
    k_fill<<<EB, 256, 0, stream>>>(src, dst, ew, rowptr, rank, cw);

    // layer 1
    k_agg16<<<NWB, 256, 0, stream>>>(xb, rowptr, cw, agg);
    k_gemm_mfma<<<GB, 256, 0, stream>>>(agg, x, W1hi, W1lo, b1l,
                                        bn1g, bn1b, bn1m, bn1v, hA, hA16);
    // layer 2
    k_agg16<<<NWB, 256, 0, stream>>>(hA16, rowptr, cw, agg);
    k_gemm_mfma<<<GB, 256, 0, stream>>>(agg, hA, W2hi, W2lo, b2l,
                                        bn2g, bn2b, bn2m, bn2v, hB, nullptr);
    // layer 3 (transform-then-aggregate: only 2 floats/edge)
    k_lin3<<<NWB, 256, 0, stream>>>(hB, w3l, w3r, t4);
    k_out<<<NWB, 256, 0, stream>>>(t4, rowptr, cw, b3l, out);
}